// Round 5
// baseline (288.637 us; speedup 1.0000x reference)
//
#include <hip/hip_runtime.h>
#include <hip/hip_bf16.h>

#define BATCH 2
#define SEQ 2048
#define HID 2048
#define NH 32
#define NKVH 8
#define HD 64
#define GQ 4
#define ROT 32

typedef __attribute__((ext_vector_type(8))) short bf16x8;
typedef __attribute__((ext_vector_type(8))) unsigned short u16x8;
typedef __attribute__((ext_vector_type(4))) float f32x4;
typedef unsigned int u32;
typedef unsigned short u16;

#define MFMA_BF16(A, B, C) __builtin_amdgcn_mfma_f32_16x16x32_bf16(A, B, C, 0, 0, 0)

// 0.125 (1/sqrt(64)) * log2(e): folded into Q at projection time
#define QSCALE 0.180336880111120f

__device__ __forceinline__ void gload_lds16(const void* g, void* l) {
    __builtin_amdgcn_global_load_lds(
        (const __attribute__((address_space(1))) unsigned int*)g,
        (__attribute__((address_space(3))) unsigned int*)l, 16, 0, 0);
}

__device__ __forceinline__ u16 f2b(float x) {
    union { __hip_bfloat16 h; u16 u; } cv;
    cv.h = __float2bfloat16(x);
    return cv.u;
}
// round-half-up bf16 (values finite, non-NaN)
__device__ __forceinline__ u16 f2br(float x) {
    return (u16)((__builtin_bit_cast(u32, x) + 0x8000u) >> 16);
}
// round-half-up bf16x2 pack: (hi|lo) in 3 VALU ops (values finite, non-NaN)
__device__ __forceinline__ u32 pack2r(float lo, float hi) {
    u32 a = __builtin_bit_cast(u32, lo) + 0x8000u;
    u32 b = __builtin_bit_cast(u32, hi) + 0x8000u;
    return __builtin_amdgcn_perm(b, a, 0x07060302u);
}

// ---------------------------------------------------------------------------
// One fused cast dispatch: hs, Wq, Wk, Wv, Wo -> bf16. 2048 elems per block.
// ---------------------------------------------------------------------------
__global__ __launch_bounds__(256) void cast_all(
    const float* __restrict__ hs, const float* __restrict__ Wq,
    const float* __restrict__ Wk, const float* __restrict__ Wv,
    const float* __restrict__ Wo, u16* __restrict__ d_hs, u16* __restrict__ d_Wq,
    u16* __restrict__ d_Wk, u16* __restrict__ d_Wv, u16* __restrict__ d_Wo) {
    const int bx = blockIdx.x;
    const float* s;
    u16* d;
    int off;
    if (bx < 4096) { s = hs; d = d_hs; off = bx; }
    else if (bx < 6144) { s = Wq; d = d_Wq; off = bx - 4096; }
    else if (bx < 6656) { s = Wk; d = d_Wk; off = bx - 6144; }
    else if (bx < 7168) { s = Wv; d = d_Wv; off = bx - 6656; }
    else { s = Wo; d = d_Wo; off = bx - 7168; }
    const size_t i = (size_t)off * 2048 + threadIdx.x * 8;
    const float4 a = *(const float4*)&s[i];
    const float4 b = *(const float4*)&s[i + 4];
    u16x8 v;
    v[0] = f2b(a.x); v[1] = f2b(a.y); v[2] = f2b(a.z); v[3] = f2b(a.w);
    v[4] = f2b(b.x); v[5] = f2b(b.y); v[6] = f2b(b.z); v[7] = f2b(b.w);
    *(u16x8*)&d[i] = v;
}

// ---------------------------------------------------------------------------
// Fused QKV projection — 256x256 tile, 8 waves (2Mx4N), BK=64.
// 4-phase window per K-tile, 8 barriers/window (r2 skeleton): ph3 carries the
// window vmcnt — if staging: vmcnt(8) (tile t+1's 8 oldest loads retired,
// tile t+2's 8 stay in flight); tail (t>=30): no stages, vmcnt(0) drain.
// The barrier after ph3's MFMA doubles as next window's entry guard.
// SINGLE MFMA path for all modes (swapped operands, C^T in regs) — a
// per-mode if/else inside the MFMA chain blocks AGPR allocation of the
// 128-reg accumulator and spills it to scratch (round-1/2 failure).
// V's Vt[d][s] layout is recovered post-loop via a 128 KiB LDS transpose.
// ---------------------------------------------------------------------------
__global__ __launch_bounds__(512, 2) void qkv_gemm(
    const u16* __restrict__ A, const u16* __restrict__ Wq,
    const u16* __restrict__ Wk, const u16* __restrict__ Wv,
    u16* __restrict__ Qb, u16* __restrict__ Kb, u16* __restrict__ Vt,
    const float* __restrict__ cosp, const float* __restrict__ sinp) {
    extern __shared__ __align__(16) u16 lds[];
    u16* Asl = lds;             // [2 buf][2 half][128*64]
    u16* Wsl = lds + 32768;     // [2 buf][2 half][128*64]

    const int bid = blockIdx.x;                  // 192 blocks
    const int wg = (bid & 7) * 24 + (bid >> 3);  // bijective XCD chunk swizzle
    const int mt = wg / 12, nt = wg % 12;
    const int m0 = mt * 256;

    int mode, n0;
    const u16* __restrict__ W;
    if (nt < 8)       { mode = 0; W = Wq; n0 = nt * 256; }
    else if (nt < 10) { mode = 1; W = Wk; n0 = (nt - 8) * 256; }
    else              { mode = 2; W = Wv; n0 = (nt - 10) * 256; }

    const int tid = threadIdx.x;
    const int lane = tid & 63, w = tid >> 6;
    const int wr = w >> 2, wc = w & 3;           // 2 x 4 wave grid
    const int ar = lane & 15, quad = lane >> 4, q4 = quad * 4;

    f32x4 acc[8][4] = {};
    bf16x8 af[4][2], wf0[2][2], wf1[2][2];

// stage one quarter (64 rows = 8 KB = 1 gload/thread) of half h, tile tt,
// into ring buffer b. Global source pre-swizzled (chunk ^= row&7); LDS linear.
#define STAGE_A_Q(b, h, c, tt) { \
    const int ci_ = (c) * 512 + tid; \
    const int row_ = ci_ >> 3, kcg_ = (ci_ & 7) ^ (row_ & 7); \
    gload_lds16(&A[(size_t)(m0 + (h) * 128 + row_) * HID + (tt) * 64 + kcg_ * 8], \
                &Asl[((b) * 2 + (h)) * 8192 + ci_ * 8]); }
#define STAGE_W_Q(b, h, c, tt) { \
    const int ci_ = (c) * 512 + tid; \
    const int row_ = ci_ >> 3, kcg_ = (ci_ & 7) ^ (row_ & 7); \
    gload_lds16(&W[(size_t)(n0 + (h) * 128 + row_) * HID + (tt) * 64 + kcg_ * 8], \
                &Wsl[((b) * 2 + (h)) * 8192 + ci_ * 8]); }
// frag reads: wave wr owns A-half wr; wave's W-half = wc>>1, rows (wc&1)*64+
#define LDA_F(dst, mj, kh) { \
    const int r_ = (mj) * 16 + ar; \
    dst = *(const bf16x8*)&Asl[(cur * 2 + wr) * 8192 + r_ * 64 + \
                               ((((kh) * 4 + quad) ^ (r_ & 7)) * 8)]; }
#define LDW_F(dst, nj, kh) { \
    const int r_ = (wc & 1) * 64 + (nj) * 16 + ar; \
    dst = *(const bf16x8*)&Wsl[(cur * 2 + (wc >> 1)) * 8192 + r_ * 64 + \
                               ((((kh) * 4 + quad) ^ (r_ & 7)) * 8)]; }
// one C-quadrant (4 mi x 2 ni) x K=64: 16 MFMA. SINGLE PATH: swapped (C^T).
#define MFMA_QUAD(mh, nh, WF) \
    _Pragma("unroll") for (int kh = 0; kh < 2; ++kh) \
    _Pragma("unroll") for (int mi = 0; mi < 4; ++mi) \
    _Pragma("unroll") for (int ni = 0; ni < 2; ++ni) \
        acc[(mh) * 4 + mi][(nh) * 2 + ni] = \
            MFMA_BF16(WF[ni][kh], af[mi][kh], acc[(mh) * 4 + mi][(nh) * 2 + ni]);

    // prologue: tile 0 -> buf0 (first 8 loads), tile 1 -> buf1 (next 8).
    // vmcnt(8): tile 0 resident, tile 1 in flight.
    STAGE_A_Q(0, 0, 0, 0); STAGE_A_Q(0, 0, 1, 0);
    STAGE_A_Q(0, 1, 0, 0); STAGE_A_Q(0, 1, 1, 0);
    STAGE_W_Q(0, 0, 0, 0); STAGE_W_Q(0, 0, 1, 0);
    STAGE_W_Q(0, 1, 0, 0); STAGE_W_Q(0, 1, 1, 0);
    STAGE_A_Q(1, 0, 0, 1); STAGE_A_Q(1, 0, 1, 1);
    STAGE_A_Q(1, 1, 0, 1); STAGE_A_Q(1, 1, 1, 1);
    STAGE_W_Q(1, 0, 0, 1); STAGE_W_Q(1, 0, 1, 1);
    STAGE_W_Q(1, 1, 0, 1); STAGE_W_Q(1, 1, 1, 1);
    asm volatile("s_waitcnt vmcnt(8)" ::: "memory");
    __builtin_amdgcn_s_barrier();

#pragma unroll 2
    for (int t = 0; t < 32; ++t) {
        const int cur = t & 1;
        const bool st = (t < 30);    // windows 30/31 have nothing left to stage
        const int t2 = t + 2;
        // ---- ph0: read af rows 0-63 (half wr) + wf0; MFMA quad(0,0) ----
#pragma unroll
        for (int mi = 0; mi < 4; ++mi) { LDA_F(af[mi][0], mi, 0); LDA_F(af[mi][1], mi, 1); }
#pragma unroll
        for (int ni = 0; ni < 2; ++ni) { LDW_F(wf0[ni][0], ni, 0); LDW_F(wf0[ni][1], ni, 1); }
        __builtin_amdgcn_s_barrier();
        asm volatile("s_waitcnt lgkmcnt(0)" ::: "memory");
        __builtin_amdgcn_s_setprio(1);
        MFMA_QUAD(0, 0, wf0);
        __builtin_amdgcn_s_setprio(0);
        __builtin_amdgcn_s_barrier();
        // ---- ph1: read wf1; stage A(t+2) c0 (both halves); MFMA quad(0,1) ----
#pragma unroll
        for (int ni = 0; ni < 2; ++ni) { LDW_F(wf1[ni][0], 2 + ni, 0); LDW_F(wf1[ni][1], 2 + ni, 1); }
        if (st) { STAGE_A_Q(cur, 0, 0, t2); STAGE_A_Q(cur, 1, 0, t2); }
        __builtin_amdgcn_s_barrier();
        asm volatile("s_waitcnt lgkmcnt(0)" ::: "memory");
        __builtin_amdgcn_s_setprio(1);
        MFMA_QUAD(0, 1, wf1);
        __builtin_amdgcn_s_setprio(0);
        __builtin_amdgcn_s_barrier();
        // ---- ph2: read af rows 64-127; stage W(t+2) h0; MFMA quad(1,1) ----
#pragma unroll
        for (int mi = 0; mi < 4; ++mi) { LDA_F(af[mi][0], 4 + mi, 0); LDA_F(af[mi][1], 4 + mi, 1); }
        if (st) { STAGE_W_Q(cur, 0, 0, t2); STAGE_W_Q(cur, 0, 1, t2); }
        __builtin_amdgcn_s_barrier();
        asm volatile("s_waitcnt lgkmcnt(0)" ::: "memory");
        __builtin_amdgcn_s_setprio(1);
        MFMA_QUAD(1, 1, wf1);
        __builtin_amdgcn_s_setprio(0);
        __builtin_amdgcn_s_barrier();
        // ---- ph3: stage A(t+2) c1 + W(t+2) h1; window vmcnt; MFMA quad(1,0).
        //      Post-MFMA barrier doubles as next window's entry guard. ----
        if (st) {
            STAGE_A_Q(cur, 0, 1, t2); STAGE_A_Q(cur, 1, 1, t2);
            STAGE_W_Q(cur, 1, 0, t2); STAGE_W_Q(cur, 1, 1, t2);
            // tile t+1's 8 loads (oldest) retired; tile t+2's 8 stay in flight
            asm volatile("s_waitcnt vmcnt(8)" ::: "memory");
        } else {
            asm volatile("s_waitcnt vmcnt(0)" ::: "memory");
        }
        __builtin_amdgcn_s_barrier();
        __builtin_amdgcn_s_setprio(1);
        MFMA_QUAD(1, 0, wf0);
        __builtin_amdgcn_s_setprio(0);
        __builtin_amdgcn_s_barrier();
    }

#undef STAGE_A_Q
#undef STAGE_W_Q
#undef LDA_F
#undef LDW_F
#undef MFMA_QUAD

    // C^T regs (all modes): acc[mi][ni][r] =
    //   C[token = m0+wr*128+mi*16+ar][col = n0+wc*64+ni*16+q4+r]
    if (mode < 2) {
        const float SC = (mode == 0) ? QSCALE : 1.0f;
        u16* __restrict__ C = (mode == 0) ? Qb : Kb;
        const int N = (mode == 0) ? 2048 : 512;
#pragma unroll
        for (int mi = 0; mi < 8; ++mi) {
            const int t = m0 + wr * 128 + mi * 16 + ar;
            const float4 c0 = *(const float4*)&cosp[(size_t)t * ROT + q4];
            const float4 s0 = *(const float4*)&sinp[(size_t)t * ROT + q4];
            const float4 c1 = *(const float4*)&cosp[(size_t)t * ROT + 16 + q4];
            const float4 s1 = *(const float4*)&sinp[(size_t)t * ROT + 16 + q4];
            u16* crow = &C[(size_t)t * N + n0 + wc * 64];
            const f32x4 x0 = acc[mi][0], x1 = acc[mi][1];
            const float cr0[4] = {c0.x, c0.y, c0.z, c0.w};
            const float sr0[4] = {s0.x, s0.y, s0.z, s0.w};
            const float cr1[4] = {c1.x, c1.y, c1.z, c1.w};
            const float sr1[4] = {s1.x, s1.y, s1.z, s1.w};
            float o0[4], o1[4];
#pragma unroll
            for (int r = 0; r < 4; ++r) {
                o0[r] = (x0[r] * cr0[r] - x1[r] * sr0[r]) * SC;
                o1[r] = (x1[r] * cr1[r] + x0[r] * sr1[r]) * SC;
            }
            uint2 v;
            v.x = pack2r(o0[0], o0[1]); v.y = pack2r(o0[2], o0[3]);
            *(uint2*)&crow[q4] = v;
            v.x = pack2r(o1[0], o1[1]); v.y = pack2r(o1[2], o1[3]);
            *(uint2*)&crow[16 + q4] = v;
            v.x = pack2r(acc[mi][2][0] * SC, acc[mi][2][1] * SC);
            v.y = pack2r(acc[mi][2][2] * SC, acc[mi][2][3] * SC);
            *(uint2*)&crow[32 + q4] = v;
            v.x = pack2r(acc[mi][3][0] * SC, acc[mi][3][1] * SC);
            v.y = pack2r(acc[mi][3][2] * SC, acc[mi][3][3] * SC);
            *(uint2*)&crow[48 + q4] = v;
        }
    } else {
        // V epilogue: transpose C^T -> Vt[d][s] through LDS (staging LDS dead).
        // Lt[vcol][tok ^ xsw(vcol)], xsw = ((vcol>>2)&3)<<4 (bank-spreads quads).
        u16* Lt = lds;  // 256 x 256 bf16 = 128 KiB
        __syncthreads();   // all waves' outstanding gloads drained (ph3 vmcnt(0))
#pragma unroll
        for (int mi = 0; mi < 8; ++mi) {
            const int tok = wr * 128 + mi * 16 + ar;
#pragma unroll
            for (int ni = 0; ni < 4; ++ni) {
                const int vc = wc * 64 + ni * 16 + q4;
#pragma unroll
                for (int r = 0; r < 4; ++r) {
                    const int vcol = vc + r;
                    const int ti = tok ^ (((vcol >> 2) & 3) << 4);
                    Lt[vcol * 256 + ti] = f2br(acc[mi][ni][r]);
                }
            }
        }
        __syncthreads();
        // read back token-contiguous; store coalesced with pi relabeling
        for (int it = 0; it < 32; ++it) {
            const int vcol = it * 8 + w;
            const int gcol = n0 + vcol;
            const int kvh = gcol >> 6, d = gcol & 63;
            const int xsw = ((vcol >> 2) & 3) << 4;
            const int s0l = lane * 4;
            const uint2 vv = *(const uint2*)&Lt[vcol * 256 + (s0l ^ xsw)];
            const int g = m0 + s0l;
            const int bb = g >> 11;
            const int s = g & 2047;
            const int ca = (s >> 2) & 7;
            const int cl = ((ca & 3) << 1) | (ca >> 2);
            const int spos = (s & ~31) + cl * 4;
            *(uint2*)&Vt[((size_t)(bb * NKVH + kvh) * HD + d) * SEQ + spos] = vv;
        }
    }
}

// ---------------------------------------------------------------------------
// O projection: C[M,N] = A[M,K] @ W[N,K]^T, fp32 out. BK=64, swapped operands
// -> lane owns 4 consecutive n -> float4 stores. XCD swizzle: 2 n-tiles/xcd.
// ---------------------------------------------------------------------------
__global__ __launch_bounds__(256) void gemm_bt(const u16* __restrict__ A,
                                               const u16* __restrict__ W,
                                               float* __restrict__ C,
                                               int M, int N, int K) {
    const int bid = blockIdx.x;
    const int xcd = bid & 7, loc = bid >> 3;   // 64 locals per xcd
    const int n0 = (xcd * 2 + (loc & 1)) * 128;
    const int m0 = (loc >> 1) * 128;

    __shared__ __align__(16) u16 As[128 * 64];
    __shared__ __align__(16) u16 Ws[128 * 64];
    const int tid = threadIdx.x;
    const int lane = tid & 63, wave = tid >> 6;
    const int ar = lane & 15, quad = lane >> 4;
    const int q4 = quad * 4;
    const int wm = (wave >> 1) * 64, wn = (wave & 1) * 64;

    f32x4 acc[4][4] = {};

    for (int k0 = 0; k0 < K; k0 += 64) {
#pragma unroll
        for (int it = 0; it < 4; ++it) {
            const int ci = it * 256 + tid;
            const int row = ci >> 3, kcl = ci & 7;
            const int kcg = kcl ^ (row & 7);
            gload_lds16(&A[(size_t)(m0 + row) * K + k0 + kcg * 8], &As[ci * 8]);
            gload_lds16(&W[(size_t)(n0 + row) * K + k0 + kcg * 8], &Ws[ci * 8]);
        }
        __syncthreads();
#pragma unroll
        for (int kh = 0; kh < 2; ++kh) {
            bf16x8 af[4], bf[4];
#pragma unroll
            for (int t = 0; t < 4; ++t) {
                const int ra = wm + t * 16 + ar;
                af[t] = *(const bf16x8*)&As[ra * 64 + (((kh * 4 + quad) ^ (ra & 7))) * 8];
                const int rb = wn + t * 16 + ar;
                bf[t] = *(const bf16x8*)&Ws[rb * 64 + (((kh * 4 + quad) ^ (rb & 7))) * 8];
            }
#pragma unroll
            for (int mt = 0; mt < 4; ++mt)
#pragma unroll
                for (int nt = 0; nt < 4; ++nt)
                    acc[mt][nt] = MFMA_BF16(bf[nt], af[mt], acc[mt][nt]);  // C^T
        }
        __syncthreads();
    }

    // C^T regs: acc[mt][nt][r] = C[m0+wm+mt*16+ar][n0+wn+nt*16+q4+r]
#pragma unroll
    for (int mt = 0; mt < 4; ++mt) {
        const int t = m0 + wm + mt * 16 + ar;
#pragma unroll
        for (int nt = 0; nt < 4; ++nt) {
            float4 v = {acc[mt][nt][0], acc[mt][nt][1], acc[mt][nt][2], acc[mt][nt][3]};
            *(float4*)&C[(size_t)t * N + n0 + wn + nt * 16 + q4] = v;
        }
    }
}

// ---------------------------------------------------------------------------
// Flash attention, S^T formulation, causal-balanced: block p handles q-tiles
// p and 15-p (uniform 34 kv-iters). 128 q rows per phase, 32/wave.
// S^T = K*Q^T (lane owns q); O^T = V^T*P^T (own post-exp regs ARE the P^T
// B-frag under the kv relabeling baked into Vt). Max-free streaming softmax.
// VALU cuts (r4): raw v_exp_f32, zero-C first MFMA, hoisted rofs/gptrs.
// r5: setprio(1) around both MFMA clusters (T5 — attn blocks are
// independent, the regime where setprio measured +4-7%).
// ---------------------------------------------------------------------------
__global__ __launch_bounds__(256, 2) void flash_attn_mfma(
    const u16* __restrict__ Qg, const u16* __restrict__ Kg,
    const u16* __restrict__ Vtg, u16* __restrict__ AO) {
    const int p = blockIdx.x, h = blockIdx.y, b = blockIdx.z;
    const int kvh = h / GQ;
    const int tid = threadIdx.x;
    const int lane = tid & 63, w = tid >> 6;
    const int n = lane & 15, quad = lane >> 4;

    __shared__ __align__(16) u16 Qs[128 * 64];
    __shared__ __align__(16) u16 Ks[2 * 64 * 64];
    __shared__ __align__(16) u16 Vts[2 * 64 * 64];

    // hoisted LDS fragment offsets: rofs[j][t16] for row=t16*16+n, chunk j
    // (same formula serves K reads [kh][krow] and V reads [kb][drow])
    int rofs[2][4];
#pragma unroll
    for (int j = 0; j < 2; ++j)
#pragma unroll
        for (int t16 = 0; t16 < 4; ++t16) {
            const int row = t16 * 16 + n;
            rofs[j][t16] = row * 64 + (((j * 4 + quad) ^ (row & 7)) * 8);
        }

    // hoisted global staging pointers (per-thread, kv-tile 0)
    const int ci0 = tid, ci1 = 256 + tid;
    const int row0 = ci0 >> 3, kcg0 = (ci0 & 7) ^ (row0 & 7);
    const int row1 = ci1 >> 3, kcg1 = (ci1 & 7) ^ (row1 & 7);
    const u16* kg0 = &Kg[(size_t)((b * SEQ + row0) * NKVH + kvh) * HD + kcg0 * 8];
    const u16* kg1 = &Kg[(size_t)((b * SEQ + row1) * NKVH + kvh) * HD + kcg1 * 8];
    const u16* vg0 = &Vtg[(size_t)((b * NKVH + kvh) * HD + row0) * SEQ + kcg0 * 8];
    const u16* vg1 = &Vtg[(size_t)((b * NKVH + kvh) * HD + row1) * SEQ + kcg1 * 8];
    const f32x4 kZ = {0.f, 0.f, 0.f, 0.f};

    for (int ph = 0; ph < 2; ++ph) {
        const int bq = ph ? (15 - p) : p;
        const int q0 = bq * 128;

        // stage Q (128x64) and K/V tile 0 into buffer 0 (chunk ^= row&7)
#pragma unroll
        for (int it = 0; it < 4; ++it) {
            const int ci = it * 256 + tid;
            const int row = ci >> 3, kcg = (ci & 7) ^ (row & 7);
            gload_lds16(&Qg[(size_t)((b * SEQ + q0 + row) * NH + h) * HD + kcg * 8],
                        &Qs[ci * 8]);
        }
        gload_lds16(kg0, &Ks[ci0 * 8]);
        gload_lds16(kg1, &Ks[ci1 * 8]);
        gload_lds16(vg0, &Vts[ci0 * 8]);
        gload_lds16(vg1, &Vts[ci1 * 8]);
        __syncthreads();

        // hoist Q^T B-frags
        bf16x8 Qf[2][2];
#pragma unroll
        for (int t = 0; t < 2; ++t)
#pragma unroll
            for (int kh = 0; kh < 2; ++kh) {
                const int qrow = w * 32 + t * 16 + n;
                const int c = (kh * 4 + quad) ^ (qrow & 7);
                Qf[t][kh] = *(const bf16x8*)&Qs[qrow * 64 + c * 8];
            }

        f32x4 O[2][4] = {};
        float lsum[2] = {0.f, 0.f};

        const int ktmax = 2 * bq + 1;
        for (int kt = 0; kt <= ktmax; ++kt) {
            const int cur = kt & 1;
            if (kt < ktmax) {  // prefetch next K/V tile into other buffer
                const int base = (cur ^ 1) * 4096;
                const size_t ko = (size_t)(kt + 1) * (64 * NKVH * HD);
                const size_t vo = (size_t)(kt + 1) * 64;
                gload_lds16(kg0 + ko, &Ks[base + ci0 * 8]);
                gload_lds16(kg1 + ko, &Ks[base + ci1 * 8]);
                gload_lds16(vg0 + vo, &Vts[base + ci0 * 8]);
                gload_lds16(vg1 + vo, &Vts[base + ci1 * 8]);
            }
            const u16* Kl = &Ks[cur * 4096];
            const u16* Vl = &Vts[cur * 4096];

            // S^T (log2-scaled domain; Q pre-scaled); zero-C first MFMA
            f32x4 sc[2][4];
            __builtin_amdgcn_s_setprio(1);
#pragma unroll
            for (int k4 = 0; k4 < 4; ++k4) {
                const bf16x8 Kf0 = *(const bf16x8*)&Kl[rofs[0][k4]];
                sc[0][k4] = MFMA_BF16(Kf0, Qf[0][0], kZ);
                sc[1][k4] = MFMA_BF16(Kf0, Qf[1][0], kZ);
                const bf16x8 Kf1 = *(const bf16x8*)&Kl[rofs[1][k4]];
                sc[0][k4] = MFMA_BF16(Kf1, Qf[0][1], sc[0][k4]);
                sc[1][k4] = MFMA_BF16(Kf1, Qf[1][1], sc[1][k4]);
            }
            __builtin_amdgcn_s_setprio(0);

            const bool masked = (kt >= 2 * bq);
            bf16x8 Pf[2][2];
#pragma unroll
            for (int t = 0; t < 2; ++t) {
                const int qg = q0 + w * 32 + t * 16 + n;
                if (masked) {
#pragma unroll
                    for (int k4 = 0; k4 < 4; ++k4)
#pragma unroll
                        for (int r = 0; r < 4; ++r)
                            if (kt * 64 + k4 * 16 + quad * 4 + r > qg)
                                sc[t][k4][r] = -1e30f;  // exp2 -> 0
                }
                float sk[4];
#pragma unroll
                for (int k4 = 0; k4 < 4; ++k4) {
                    const float e0 = __builtin_amdgcn_exp2f(sc[t][k4][0]);
                    const float e1 = __builtin_amdgcn_exp2f(sc[t][k4][1]);
                    const float e2 = __builtin_amdgcn_exp2f(sc[t][k4][2]);
                    const float e3 = __builtin_amdgcn_exp2f(sc[t][k4][3]);
                    sc[t][k4][0] = e0; sc[t][k4][1] = e1;
                    sc[t][k4][2] = e2; sc[t][k4][3] = e3;
                    sk[k4] = (e0 + e1) + (e2 + e3);
                }
                lsum[t] += (sk[0] + sk[1]) + (sk[2] + sk[3]);
#pragma unroll
                for (int kb = 0; kb < 2; ++kb) {
                    union { u32 uw[4]; bf16x8 v; } cv;
#pragma unroll
                    for (int a = 0; a < 2; ++a) {
                        cv.uw[a * 2 + 0] = pack2r(sc[t][2 * kb + a][0], sc[t][2 * kb + a][1]);
                        cv.uw[a * 2 + 1] = pack2r(sc[t][2 * kb + a][2], sc[t][2 * kb + a][3]);
                    }
                    Pf[t][kb] = cv.v;
                }
            }

            // O^T += V^T * P^T
            __builtin_amdgcn_s_setprio(1);
#pragma unroll
            for (int kb = 0; kb < 2; ++kb)
#pragma unroll
                for (int dt = 0; dt < 4; ++dt) {
                    const bf16x8 Vf = *(const bf16x8*)&Vl[rofs[kb][dt]];
                    O[0][dt] = MFMA_BF16(Vf, Pf[0][kb], O[0][dt]);
                    O[1][dt] = MFMA_BF16(Vf, Pf[1][kb], O[1][dt]);
                }
            __builtin_amdgcn_s_setprio(0);
            __syncthreads();
        }

        // epilogue: reduce l across quads once; O^T regs: d=dt*16+quad*4+r, q=n
#pragma unroll
        for (int t = 0; t < 2; ++t) {
            float rs = lsum[t];
            rs += __shfl_xor(rs, 16, 64);
            rs += __shfl_xor(rs, 32, 64);
            const int qg = q0 + w * 32 + t * 16 + n;
            const float inv = 1.f / rs;
#pragma unroll
            for (int dt = 0; dt < 4; ++dt) {
                uint2 v2;
                v2.x = pack2r(O[t][dt][0] * inv, O[t][dt][1] * inv);
                v2.y = pack2r(O[t][dt][2] * inv, O[t][dt][3] * inv);
                *(uint2*)&AO[(size_t)((b * SEQ + qg) * NH + h) * HD + dt * 16 + quad * 4] = v2;
            }
        }
    }
}

// ---------------------------------------------------------------------------
extern "C" void kernel_launch(void* const* d_in, const int* in_sizes, int n_in,
                              void* d_out, int out_size, void* d_ws,
                              size_t ws_size, hipStream_t stream) {
    const float* hs = (const float*)d_in[0];
    const float* cosp = (const float*)d_in[1];
    const float* sinp = (const float*)d_in[2];
    // d_in[3] attention_mask: pure causal, handled in-kernel
    const float* Wq = (const float*)d_in[4];
    const float* Wk = (const float*)d_in[5];
    const float* Wv = (const float*)d_in[6];
    const float* Wo = (const float*)d_in[7];
    float* out = (float*)d_out;

    u16* ws = (u16*)d_ws;
    u16* hs_bf = ws;
    u16* Wq_bf = hs_bf + (size_t)4096 * 2048;
    u16* Wk_bf = Wq_bf + (size_t)2048 * 2048;
    u16* Wv_bf = Wk_bf + (size_t)512 * 2048;
    u16* Wo_bf = Wv_bf + (size_t)512 * 2048;
    u16* Qb = Wo_bf + (size_t)2048 * 2048;
    u16* Kb = Qb + (size_t)4096 * 2048;
    u16* Vt = Kb + (size_t)4096 * 512;
    u16* AO = hs_bf;  // alias: hs_bf dead after QKV projection

    // one-time opt-in for 128 KiB dynamic LDS (host-side state change; not a
    // stream op, safe under graph capture)
    static bool attr_done = false;
    if (!attr_done) {
        hipFuncSetAttribute(reinterpret_cast<const void*>(qkv_gemm),
                            hipFuncAttributeMaxDynamicSharedMemorySize, 131072);
        attr_done = true;
    }

    cast_all<<<dim3(9216), 256, 0, stream>>>(hs, Wq, Wk, Wv, Wo, hs_bf, Wq_bf,
                                             Wk_bf, Wv_bf, Wo_bf);

    qkv_gemm<<<dim3(192), 512, 131072, stream>>>(hs_bf, Wq_bf, Wk_bf, Wv_bf,
                                                 Qb, Kb, Vt, cosp, sinp);

    flash_attn_mfma<<<dim3(8, NH, BATCH), 256, 0, stream>>>(Qb, Kb, Vt, AO);

    gemm_bt<<<dim3(512), 256, 0, stream>>>(AO, Wo_bf, out, 4096, 2048, 2048);
}

// Round 6
// 288.426 us; speedup vs baseline: 1.0007x; 1.0007x over previous
//
#include <hip/hip_runtime.h>
#include <hip/hip_bf16.h>

#define BATCH 2
#define SEQ 2048
#define HID 2048
#define NH 32
#define NKVH 8
#define HD 64
#define GQ 4
#define ROT 32

typedef __attribute__((ext_vector_type(8))) short bf16x8;
typedef __attribute__((ext_vector_type(8))) unsigned short u16x8;
typedef __attribute__((ext_vector_type(4))) float f32x4;
typedef unsigned int u32;
typedef unsigned short u16;

#define MFMA_BF16(A, B, C) __builtin_amdgcn_mfma_f32_16x16x32_bf16(A, B, C, 0, 0, 0)

// 0.125 (1/sqrt(64)) * log2(e): folded into Q at projection time
#define QSCALE 0.180336880111120f

__device__ __forceinline__ void gload_lds16(const void* g, void* l) {
    __builtin_amdgcn_global_load_lds(
        (const __attribute__((address_space(1))) unsigned int*)g,
        (__attribute__((address_space(3))) unsigned int*)l, 16, 0, 0);
}

__device__ __forceinline__ u16 f2b(float x) {
    union { __hip_bfloat16 h; u16 u; } cv;
    cv.h = __float2bfloat16(x);
    return cv.u;
}
// round-half-up bf16 (values finite, non-NaN)
__device__ __forceinline__ u16 f2br(float x) {
    return (u16)((__builtin_bit_cast(u32, x) + 0x8000u) >> 16);
}
// round-half-up bf16x2 pack: (hi|lo) in 3 VALU ops (values finite, non-NaN)
__device__ __forceinline__ u32 pack2r(float lo, float hi) {
    u32 a = __builtin_bit_cast(u32, lo) + 0x8000u;
    u32 b = __builtin_bit_cast(u32, hi) + 0x8000u;
    return __builtin_amdgcn_perm(b, a, 0x07060302u);
}

// ---------------------------------------------------------------------------
// One fused cast dispatch: hs, Wq, Wk, Wv, Wo -> bf16. 2048 elems per block.
// ---------------------------------------------------------------------------
__global__ __launch_bounds__(256) void cast_all(
    const float* __restrict__ hs, const float* __restrict__ Wq,
    const float* __restrict__ Wk, const float* __restrict__ Wv,
    const float* __restrict__ Wo, u16* __restrict__ d_hs, u16* __restrict__ d_Wq,
    u16* __restrict__ d_Wk, u16* __restrict__ d_Wv, u16* __restrict__ d_Wo) {
    const int bx = blockIdx.x;
    const float* s;
    u16* d;
    int off;
    if (bx < 4096) { s = hs; d = d_hs; off = bx; }
    else if (bx < 6144) { s = Wq; d = d_Wq; off = bx - 4096; }
    else if (bx < 6656) { s = Wk; d = d_Wk; off = bx - 6144; }
    else if (bx < 7168) { s = Wv; d = d_Wv; off = bx - 6656; }
    else { s = Wo; d = d_Wo; off = bx - 7168; }
    const size_t i = (size_t)off * 2048 + threadIdx.x * 8;
    const float4 a = *(const float4*)&s[i];
    const float4 b = *(const float4*)&s[i + 4];
    u16x8 v;
    v[0] = f2b(a.x); v[1] = f2b(a.y); v[2] = f2b(a.z); v[3] = f2b(a.w);
    v[4] = f2b(b.x); v[5] = f2b(b.y); v[6] = f2b(b.z); v[7] = f2b(b.w);
    *(u16x8*)&d[i] = v;
}

// ---------------------------------------------------------------------------
// Fused QKV projection — 256x256 tile, 8 waves (2Mx4N), BK=64.
// r6: TWO merged phases per K-tile window (was 4): 4 barriers + 2 lgkm
// drains per window instead of 8 + 3 (r5 PMC: MfmaUtil 26% with LDS-BW cap
// ~58% — the gap was barrier/lgkm stall exposure at 1 block/CU).
//   ph01 = {read af rows 0-63 + wf0 + wf1 (16 ds_read); stage A-c1(t+1);
//           barrier; lgkm0; 32 MFMA quads (0,0)+(0,1); barrier}
//   ph23 = {read af rows 64-127 (8 ds_read); stage A-c0+W (6) of t+2;
//           vmcnt(8); barrier; lgkm0; 32 MFMA quads (1,1)+(1,0);
//           vmcnt(8) [entry guard t+1]; barrier}
// Ring invariants: A-c0+W of buffer cur die at ph01's lgkm -> restaged in
// ph23 (tile t+2); A-c1 dies at ph23's lgkm -> restaged next window's ph01
// (tile t+1, buffer cur^1). vmcnt(8) = "all but 8 newest done"; the 8
// newest at every wait are this window's own issues, never needed yet.
// Tail: t=30 end vmcnt(2), t=31 vmcnt(0). Prologue per tile: Ac0 x2, W x4,
// Ac1 x2 (Ac1 last, so entry vmcnt(8) of window 1 leaves only Ac1+ph23 out).
// SINGLE MFMA path for all modes (swapped, C^T in regs) — per-mode branch
// in the MFMA chain spills the 128-reg acc (round-1/2 failure).
// V's Vt[d][s] recovered post-loop via a 128 KiB LDS transpose.
// ---------------------------------------------------------------------------
__global__ __launch_bounds__(512, 2) void qkv_gemm(
    const u16* __restrict__ A, const u16* __restrict__ Wq,
    const u16* __restrict__ Wk, const u16* __restrict__ Wv,
    u16* __restrict__ Qb, u16* __restrict__ Kb, u16* __restrict__ Vt,
    const float* __restrict__ cosp, const float* __restrict__ sinp) {
    extern __shared__ __align__(16) u16 lds[];
    u16* Asl = lds;             // [2 buf][2 half][128*64]
    u16* Wsl = lds + 32768;     // [2 buf][2 half][128*64]

    const int bid = blockIdx.x;                  // 192 blocks
    const int wg = (bid & 7) * 24 + (bid >> 3);  // bijective XCD chunk swizzle
    const int mt = wg / 12, nt = wg % 12;
    const int m0 = mt * 256;

    int mode, n0;
    const u16* __restrict__ W;
    if (nt < 8)       { mode = 0; W = Wq; n0 = nt * 256; }
    else if (nt < 10) { mode = 1; W = Wk; n0 = (nt - 8) * 256; }
    else              { mode = 2; W = Wv; n0 = (nt - 10) * 256; }

    const int tid = threadIdx.x;
    const int lane = tid & 63, w = tid >> 6;
    const int wr = w >> 2, wc = w & 3;           // 2 x 4 wave grid
    const int ar = lane & 15, quad = lane >> 4, q4 = quad * 4;

    f32x4 acc[8][4] = {};
    bf16x8 af[4][2], wf0[2][2], wf1[2][2];

// stage one quarter (64 rows = 8 KB = 1 gload/thread) of half h, tile tt,
// into ring buffer b. Global source pre-swizzled (chunk ^= row&7); LDS linear.
#define STAGE_A_Q(b, h, c, tt) { \
    const int ci_ = (c) * 512 + tid; \
    const int row_ = ci_ >> 3, kcg_ = (ci_ & 7) ^ (row_ & 7); \
    gload_lds16(&A[(size_t)(m0 + (h) * 128 + row_) * HID + (tt) * 64 + kcg_ * 8], \
                &Asl[((b) * 2 + (h)) * 8192 + ci_ * 8]); }
#define STAGE_W_Q(b, h, c, tt) { \
    const int ci_ = (c) * 512 + tid; \
    const int row_ = ci_ >> 3, kcg_ = (ci_ & 7) ^ (row_ & 7); \
    gload_lds16(&W[(size_t)(n0 + (h) * 128 + row_) * HID + (tt) * 64 + kcg_ * 8], \
                &Wsl[((b) * 2 + (h)) * 8192 + ci_ * 8]); }
// frag reads: wave wr owns A-half wr; wave's W-half = wc>>1, rows (wc&1)*64+
#define LDA_F(dst, mj, kh) { \
    const int r_ = (mj) * 16 + ar; \
    dst = *(const bf16x8*)&Asl[(cur * 2 + wr) * 8192 + r_ * 64 + \
                               ((((kh) * 4 + quad) ^ (r_ & 7)) * 8)]; }
#define LDW_F(dst, nj, kh) { \
    const int r_ = (wc & 1) * 64 + (nj) * 16 + ar; \
    dst = *(const bf16x8*)&Wsl[(cur * 2 + (wc >> 1)) * 8192 + r_ * 64 + \
                               ((((kh) * 4 + quad) ^ (r_ & 7)) * 8)]; }
// one C-quadrant (4 mi x 2 ni) x K=64: 16 MFMA. SINGLE PATH: swapped (C^T).
#define MFMA_QUAD(mh, nh, WF) \
    _Pragma("unroll") for (int kh = 0; kh < 2; ++kh) \
    _Pragma("unroll") for (int mi = 0; mi < 4; ++mi) \
    _Pragma("unroll") for (int ni = 0; ni < 2; ++ni) \
        acc[(mh) * 4 + mi][(nh) * 2 + ni] = \
            MFMA_BF16(WF[ni][kh], af[mi][kh], acc[(mh) * 4 + mi][(nh) * 2 + ni]);

    // prologue: tile 0 -> buf0, tile 1 -> buf1; per tile order Ac0,W,Ac1
    // (Ac1 last so entry vmcnt(8) retires Ac0+W first).
    STAGE_A_Q(0, 0, 0, 0); STAGE_A_Q(0, 1, 0, 0);
    STAGE_W_Q(0, 0, 0, 0); STAGE_W_Q(0, 0, 1, 0);
    STAGE_W_Q(0, 1, 0, 0); STAGE_W_Q(0, 1, 1, 0);
    STAGE_A_Q(0, 0, 1, 0); STAGE_A_Q(0, 1, 1, 0);
    STAGE_A_Q(1, 0, 0, 1); STAGE_A_Q(1, 1, 0, 1);
    STAGE_W_Q(1, 0, 0, 1); STAGE_W_Q(1, 0, 1, 1);
    STAGE_W_Q(1, 1, 0, 1); STAGE_W_Q(1, 1, 1, 1);
    STAGE_A_Q(1, 0, 1, 1); STAGE_A_Q(1, 1, 1, 1);
    asm volatile("s_waitcnt vmcnt(8)" ::: "memory");
    __builtin_amdgcn_s_barrier();

#pragma unroll 2
    for (int t = 0; t < 32; ++t) {
        const int cur = t & 1;
        // ---- ph01: read af rows 0-63 + wf0 + wf1; stage A-c1(t+1);
        //      MFMA quads (0,0)+(0,1) ----
#pragma unroll
        for (int mi = 0; mi < 4; ++mi) { LDA_F(af[mi][0], mi, 0); LDA_F(af[mi][1], mi, 1); }
#pragma unroll
        for (int ni = 0; ni < 2; ++ni) { LDW_F(wf0[ni][0], ni, 0); LDW_F(wf0[ni][1], ni, 1); }
#pragma unroll
        for (int ni = 0; ni < 2; ++ni) { LDW_F(wf1[ni][0], 2 + ni, 0); LDW_F(wf1[ni][1], 2 + ni, 1); }
        if (t >= 1 && t <= 30) {  // tiles 0/1 fully staged in prologue
            STAGE_A_Q(cur ^ 1, 0, 1, t + 1); STAGE_A_Q(cur ^ 1, 1, 1, t + 1);
        }
        __builtin_amdgcn_s_barrier();
        asm volatile("s_waitcnt lgkmcnt(0)" ::: "memory");
        __builtin_amdgcn_s_setprio(1);
        MFMA_QUAD(0, 0, wf0);
        MFMA_QUAD(0, 1, wf1);
        __builtin_amdgcn_s_setprio(0);
        __builtin_amdgcn_s_barrier();
        // ---- ph23: read af rows 64-127; stage A-c0 + W (6) of t+2;
        //      MFMA quads (1,1)+(1,0); trailing vmcnt = entry guard t+1 ----
#pragma unroll
        for (int mi = 0; mi < 4; ++mi) { LDA_F(af[mi][0], 4 + mi, 0); LDA_F(af[mi][1], 4 + mi, 1); }
        if (t <= 29) {
            STAGE_A_Q(cur, 0, 0, t + 2); STAGE_A_Q(cur, 1, 0, t + 2);
            STAGE_W_Q(cur, 0, 0, t + 2); STAGE_W_Q(cur, 0, 1, t + 2);
            STAGE_W_Q(cur, 1, 0, t + 2); STAGE_W_Q(cur, 1, 1, t + 2);
        }
        if (t <= 30) asm volatile("s_waitcnt vmcnt(8)" ::: "memory");
        else         asm volatile("s_waitcnt vmcnt(0)" ::: "memory");
        __builtin_amdgcn_s_barrier();
        asm volatile("s_waitcnt lgkmcnt(0)" ::: "memory");
        __builtin_amdgcn_s_setprio(1);
        MFMA_QUAD(1, 1, wf1);
        MFMA_QUAD(1, 0, wf0);
        __builtin_amdgcn_s_setprio(0);
        if (t <= 29)      asm volatile("s_waitcnt vmcnt(8)" ::: "memory");
        else if (t == 30) asm volatile("s_waitcnt vmcnt(2)" ::: "memory");
        else              asm volatile("s_waitcnt vmcnt(0)" ::: "memory");
        __builtin_amdgcn_s_barrier();
    }

#undef STAGE_A_Q
#undef STAGE_W_Q
#undef LDA_F
#undef LDW_F
#undef MFMA_QUAD

    // C^T regs (all modes): acc[mi][ni][r] =
    //   C[token = m0+wr*128+mi*16+ar][col = n0+wc*64+ni*16+q4+r]
    if (mode < 2) {
        const float SC = (mode == 0) ? QSCALE : 1.0f;
        u16* __restrict__ C = (mode == 0) ? Qb : Kb;
        const int N = (mode == 0) ? 2048 : 512;
#pragma unroll
        for (int mi = 0; mi < 8; ++mi) {
            const int t = m0 + wr * 128 + mi * 16 + ar;
            const float4 c0 = *(const float4*)&cosp[(size_t)t * ROT + q4];
            const float4 s0 = *(const float4*)&sinp[(size_t)t * ROT + q4];
            const float4 c1 = *(const float4*)&cosp[(size_t)t * ROT + 16 + q4];
            const float4 s1 = *(const float4*)&sinp[(size_t)t * ROT + 16 + q4];
            u16* crow = &C[(size_t)t * N + n0 + wc * 64];
            const f32x4 x0 = acc[mi][0], x1 = acc[mi][1];
            const float cr0[4] = {c0.x, c0.y, c0.z, c0.w};
            const float sr0[4] = {s0.x, s0.y, s0.z, s0.w};
            const float cr1[4] = {c1.x, c1.y, c1.z, c1.w};
            const float sr1[4] = {s1.x, s1.y, s1.z, s1.w};
            float o0[4], o1[4];
#pragma unroll
            for (int r = 0; r < 4; ++r) {
                o0[r] = (x0[r] * cr0[r] - x1[r] * sr0[r]) * SC;
                o1[r] = (x1[r] * cr1[r] + x0[r] * sr1[r]) * SC;
            }
            uint2 v;
            v.x = pack2r(o0[0], o0[1]); v.y = pack2r(o0[2], o0[3]);
            *(uint2*)&crow[q4] = v;
            v.x = pack2r(o1[0], o1[1]); v.y = pack2r(o1[2], o1[3]);
            *(uint2*)&crow[16 + q4] = v;
            v.x = pack2r(acc[mi][2][0] * SC, acc[mi][2][1] * SC);
            v.y = pack2r(acc[mi][2][2] * SC, acc[mi][2][3] * SC);
            *(uint2*)&crow[32 + q4] = v;
            v.x = pack2r(acc[mi][3][0] * SC, acc[mi][3][1] * SC);
            v.y = pack2r(acc[mi][3][2] * SC, acc[mi][3][3] * SC);
            *(uint2*)&crow[48 + q4] = v;
        }
    } else {
        // V epilogue: transpose C^T -> Vt[d][s] through LDS (staging LDS dead).
        // Lt[vcol][tok ^ xsw(vcol)], xsw = ((vcol>>2)&3)<<4 (bank-spreads quads).
        u16* Lt = lds;  // 256 x 256 bf16 = 128 KiB
        __syncthreads();   // all waves' outstanding gloads drained (t=31 vmcnt(0))
#pragma unroll
        for (int mi = 0; mi < 8; ++mi) {
            const int tok = wr * 128 + mi * 16 + ar;
#pragma unroll
            for (int ni = 0; ni < 4; ++ni) {
                const int vc = wc * 64 + ni * 16 + q4;
#pragma unroll
                for (int r = 0; r < 4; ++r) {
                    const int vcol = vc + r;
                    const int ti = tok ^ (((vcol >> 2) & 3) << 4);
                    Lt[vcol * 256 + ti] = f2br(acc[mi][ni][r]);
                }
            }
        }
        __syncthreads();
        // read back token-contiguous; store coalesced with pi relabeling
        for (int it = 0; it < 32; ++it) {
            const int vcol = it * 8 + w;
            const int gcol = n0 + vcol;
            const int kvh = gcol >> 6, d = gcol & 63;
            const int xsw = ((vcol >> 2) & 3) << 4;
            const int s0l = lane * 4;
            const uint2 vv = *(const uint2*)&Lt[vcol * 256 + (s0l ^ xsw)];
            const int g = m0 + s0l;
            const int bb = g >> 11;
            const int s = g & 2047;
            const int ca = (s >> 2) & 7;
            const int cl = ((ca & 3) << 1) | (ca >> 2);
            const int spos = (s & ~31) + cl * 4;
            *(uint2*)&Vt[((size_t)(bb * NKVH + kvh) * HD + d) * SEQ + spos] = vv;
        }
    }
}

// ---------------------------------------------------------------------------
// O projection: C[M,N] = A[M,K] @ W[N,K]^T, fp32 out. BK=64, swapped operands
// -> lane owns 4 consecutive n -> float4 stores. XCD swizzle: 2 n-tiles/xcd.
// ---------------------------------------------------------------------------
__global__ __launch_bounds__(256) void gemm_bt(const u16* __restrict__ A,
                                               const u16* __restrict__ W,
                                               float* __restrict__ C,
                                               int M, int N, int K) {
    const int bid = blockIdx.x;
    const int xcd = bid & 7, loc = bid >> 3;   // 64 locals per xcd
    const int n0 = (xcd * 2 + (loc & 1)) * 128;
    const int m0 = (loc >> 1) * 128;

    __shared__ __align__(16) u16 As[128 * 64];
    __shared__ __align__(16) u16 Ws[128 * 64];
    const int tid = threadIdx.x;
    const int lane = tid & 63, wave = tid >> 6;
    const int ar = lane & 15, quad = lane >> 4;
    const int q4 = quad * 4;
    const int wm = (wave >> 1) * 64, wn = (wave & 1) * 64;

    f32x4 acc[4][4] = {};

    for (int k0 = 0; k0 < K; k0 += 64) {
#pragma unroll
        for (int it = 0; it < 4; ++it) {
            const int ci = it * 256 + tid;
            const int row = ci >> 3, kcl = ci & 7;
            const int kcg = kcl ^ (row & 7);
            gload_lds16(&A[(size_t)(m0 + row) * K + k0 + kcg * 8], &As[ci * 8]);
            gload_lds16(&W[(size_t)(n0 + row) * K + k0 + kcg * 8], &Ws[ci * 8]);
        }
        __syncthreads();
#pragma unroll
        for (int kh = 0; kh < 2; ++kh) {
            bf16x8 af[4], bf[4];
#pragma unroll
            for (int t = 0; t < 4; ++t) {
                const int ra = wm + t * 16 + ar;
                af[t] = *(const bf16x8*)&As[ra * 64 + (((kh * 4 + quad) ^ (ra & 7))) * 8];
                const int rb = wn + t * 16 + ar;
                bf[t] = *(const bf16x8*)&Ws[rb * 64 + (((kh * 4 + quad) ^ (rb & 7))) * 8];
            }
#pragma unroll
            for (int mt = 0; mt < 4; ++mt)
#pragma unroll
                for (int nt = 0; nt < 4; ++nt)
                    acc[mt][nt] = MFMA_BF16(bf[nt], af[mt], acc[mt][nt]);  // C^T
        }
        __syncthreads();
    }

    // C^T regs: acc[mt][nt][r] = C[m0+wm+mt*16+ar][n0+wn+nt*16+q4+r]
#pragma unroll
    for (int mt = 0; mt < 4; ++mt) {
        const int t = m0 + wm + mt * 16 + ar;
#pragma unroll
        for (int nt = 0; nt < 4; ++nt) {
            float4 v = {acc[mt][nt][0], acc[mt][nt][1], acc[mt][nt][2], acc[mt][nt][3]};
            *(float4*)&C[(size_t)t * N + n0 + wn + nt * 16 + q4] = v;
        }
    }
}

// ---------------------------------------------------------------------------
// Flash attention, S^T formulation, causal-balanced: block p handles q-tiles
// p and 15-p (uniform 34 kv-iters). 128 q rows per phase, 32/wave.
// S^T = K*Q^T (lane owns q); O^T = V^T*P^T (own post-exp regs ARE the P^T
// B-frag under the kv relabeling baked into Vt). Max-free streaming softmax.
// VALU cuts (r4): raw v_exp_f32, zero-C first MFMA, hoisted rofs/gptrs.
// r6: setprio REMOVED — 4-wave lockstep block is m190's negative regime
// (r5 cost ~9 µs).
// ---------------------------------------------------------------------------
__global__ __launch_bounds__(256, 2) void flash_attn_mfma(
    const u16* __restrict__ Qg, const u16* __restrict__ Kg,
    const u16* __restrict__ Vtg, u16* __restrict__ AO) {
    const int p = blockIdx.x, h = blockIdx.y, b = blockIdx.z;
    const int kvh = h / GQ;
    const int tid = threadIdx.x;
    const int lane = tid & 63, w = tid >> 6;
    const int n = lane & 15, quad = lane >> 4;

    __shared__ __align__(16) u16 Qs[128 * 64];
    __shared__ __align__(16) u16 Ks[2 * 64 * 64];
    __shared__ __align__(16) u16 Vts[2 * 64 * 64];

    // hoisted LDS fragment offsets: rofs[j][t16] for row=t16*16+n, chunk j
    // (same formula serves K reads [kh][krow] and V reads [kb][drow])
    int rofs[2][4];
#pragma unroll
    for (int j = 0; j < 2; ++j)
#pragma unroll
        for (int t16 = 0; t16 < 4; ++t16) {
            const int row = t16 * 16 + n;
            rofs[j][t16] = row * 64 + (((j * 4 + quad) ^ (row & 7)) * 8);
        }

    // hoisted global staging pointers (per-thread, kv-tile 0)
    const int ci0 = tid, ci1 = 256 + tid;
    const int row0 = ci0 >> 3, kcg0 = (ci0 & 7) ^ (row0 & 7);
    const int row1 = ci1 >> 3, kcg1 = (ci1 & 7) ^ (row1 & 7);
    const u16* kg0 = &Kg[(size_t)((b * SEQ + row0) * NKVH + kvh) * HD + kcg0 * 8];
    const u16* kg1 = &Kg[(size_t)((b * SEQ + row1) * NKVH + kvh) * HD + kcg1 * 8];
    const u16* vg0 = &Vtg[(size_t)((b * NKVH + kvh) * HD + row0) * SEQ + kcg0 * 8];
    const u16* vg1 = &Vtg[(size_t)((b * NKVH + kvh) * HD + row1) * SEQ + kcg1 * 8];
    const f32x4 kZ = {0.f, 0.f, 0.f, 0.f};

    for (int ph = 0; ph < 2; ++ph) {
        const int bq = ph ? (15 - p) : p;
        const int q0 = bq * 128;

        // stage Q (128x64) and K/V tile 0 into buffer 0 (chunk ^= row&7)
#pragma unroll
        for (int it = 0; it < 4; ++it) {
            const int ci = it * 256 + tid;
            const int row = ci >> 3, kcg = (ci & 7) ^ (row & 7);
            gload_lds16(&Qg[(size_t)((b * SEQ + q0 + row) * NH + h) * HD + kcg * 8],
                        &Qs[ci * 8]);
        }
        gload_lds16(kg0, &Ks[ci0 * 8]);
        gload_lds16(kg1, &Ks[ci1 * 8]);
        gload_lds16(vg0, &Vts[ci0 * 8]);
        gload_lds16(vg1, &Vts[ci1 * 8]);
        __syncthreads();

        // hoist Q^T B-frags
        bf16x8 Qf[2][2];
#pragma unroll
        for (int t = 0; t < 2; ++t)
#pragma unroll
            for (int kh = 0; kh < 2; ++kh) {
                const int qrow = w * 32 + t * 16 + n;
                const int c = (kh * 4 + quad) ^ (qrow & 7);
                Qf[t][kh] = *(const bf16x8*)&Qs[qrow * 64 + c * 8];
            }

        f32x4 O[2][4] = {};
        float lsum[2] = {0.f, 0.f};

        const int ktmax = 2 * bq + 1;
        for (int kt = 0; kt <= ktmax; ++kt) {
            const int cur = kt & 1;
            if (kt < ktmax) {  // prefetch next K/V tile into other buffer
                const int base = (cur ^ 1) * 4096;
                const size_t ko = (size_t)(kt + 1) * (64 * NKVH * HD);
                const size_t vo = (size_t)(kt + 1) * 64;
                gload_lds16(kg0 + ko, &Ks[base + ci0 * 8]);
                gload_lds16(kg1 + ko, &Ks[base + ci1 * 8]);
                gload_lds16(vg0 + vo, &Vts[base + ci0 * 8]);
                gload_lds16(vg1 + vo, &Vts[base + ci1 * 8]);
            }
            const u16* Kl = &Ks[cur * 4096];
            const u16* Vl = &Vts[cur * 4096];

            // S^T (log2-scaled domain; Q pre-scaled); zero-C first MFMA
            f32x4 sc[2][4];
#pragma unroll
            for (int k4 = 0; k4 < 4; ++k4) {
                const bf16x8 Kf0 = *(const bf16x8*)&Kl[rofs[0][k4]];
                sc[0][k4] = MFMA_BF16(Kf0, Qf[0][0], kZ);
                sc[1][k4] = MFMA_BF16(Kf0, Qf[1][0], kZ);
                const bf16x8 Kf1 = *(const bf16x8*)&Kl[rofs[1][k4]];
                sc[0][k4] = MFMA_BF16(Kf1, Qf[0][1], sc[0][k4]);
                sc[1][k4] = MFMA_BF16(Kf1, Qf[1][1], sc[1][k4]);
            }

            const bool masked = (kt >= 2 * bq);
            bf16x8 Pf[2][2];
#pragma unroll
            for (int t = 0; t < 2; ++t) {
                const int qg = q0 + w * 32 + t * 16 + n;
                if (masked) {
#pragma unroll
                    for (int k4 = 0; k4 < 4; ++k4)
#pragma unroll
                        for (int r = 0; r < 4; ++r)
                            if (kt * 64 + k4 * 16 + quad * 4 + r > qg)
                                sc[t][k4][r] = -1e30f;  // exp2 -> 0
                }
                float sk[4];
#pragma unroll
                for (int k4 = 0; k4 < 4; ++k4) {
                    const float e0 = __builtin_amdgcn_exp2f(sc[t][k4][0]);
                    const float e1 = __builtin_amdgcn_exp2f(sc[t][k4][1]);
                    const float e2 = __builtin_amdgcn_exp2f(sc[t][k4][2]);
                    const float e3 = __builtin_amdgcn_exp2f(sc[t][k4][3]);
                    sc[t][k4][0] = e0; sc[t][k4][1] = e1;
                    sc[t][k4][2] = e2; sc[t][k4][3] = e3;
                    sk[k4] = (e0 + e1) + (e2 + e3);
                }
                lsum[t] += (sk[0] + sk[1]) + (sk[2] + sk[3]);
#pragma unroll
                for (int kb = 0; kb < 2; ++kb) {
                    union { u32 uw[4]; bf16x8 v; } cv;
#pragma unroll
                    for (int a = 0; a < 2; ++a) {
                        cv.uw[a * 2 + 0] = pack2r(sc[t][2 * kb + a][0], sc[t][2 * kb + a][1]);
                        cv.uw[a * 2 + 1] = pack2r(sc[t][2 * kb + a][2], sc[t][2 * kb + a][3]);
                    }
                    Pf[t][kb] = cv.v;
                }
            }

            // O^T += V^T * P^T
#pragma unroll
            for (int kb = 0; kb < 2; ++kb)
#pragma unroll
                for (int dt = 0; dt < 4; ++dt) {
                    const bf16x8 Vf = *(const bf16x8*)&Vl[rofs[kb][dt]];
                    O[0][dt] = MFMA_BF16(Vf, Pf[0][kb], O[0][dt]);
                    O[1][dt] = MFMA_BF16(Vf, Pf[1][kb], O[1][dt]);
                }
            __syncthreads();
        }

        // epilogue: reduce l across quads once; O^T regs: d=dt*16+quad*4+r, q=n
#pragma unroll
        for (int t = 0; t < 2; ++t) {
            float rs = lsum[t];
            rs += __shfl_xor(rs, 16, 64);
            rs += __shfl_xor(rs, 32, 64);
            const int qg = q0 + w * 32 + t * 16 + n;
            const float inv = 1.f / rs;
#pragma unroll
            for (int dt = 0; dt < 4; ++dt) {
                uint2 v2;
                v2.x = pack2r(O[t][dt][0] * inv, O[t][dt][1] * inv);
                v2.y = pack2r(O[t][dt][2] * inv, O[t][dt][3] * inv);
                *(uint2*)&AO[(size_t)((b * SEQ + qg) * NH + h) * HD + dt * 16 + quad * 4] = v2;
            }
        }
    }
}

// ---------------------------------------------------------------------------
extern "C" void kernel_launch(void* const* d_in, const int* in_sizes, int n_in,
                              void* d_out, int out_size, void* d_ws,
                              size_t ws_size, hipStream_t stream) {
    const float* hs = (const float*)d_in[0];
    const float* cosp = (const float*)d_in[1];
    const float* sinp = (const float*)d_in[2];
    // d_in[3] attention_mask: pure causal, handled in-kernel
    const float* Wq = (const float*)d_in[4];
    const float* Wk = (const float*)d_in[5];
    const float* Wv = (const float*)d_in[6];
    const float* Wo = (const float*)d_in[7];
    float* out = (float*)d_out;

    u16* ws = (u16*)d_ws;
    u16* hs_bf = ws;
    u16* Wq_bf = hs_bf + (size_t)4096 * 2048;
    u16* Wk_bf = Wq_bf + (size_t)2048 * 2048;
    u16* Wv_bf = Wk_bf + (size_t)512 * 2048;
    u16* Wo_bf = Wv_bf + (size_t)512 * 2048;
    u16* Qb = Wo_bf + (size_t)2048 * 2048;
    u16* Kb = Qb + (size_t)4096 * 2048;
    u16* Vt = Kb + (size_t)4096 * 512;
    u16* AO = hs_bf;  // alias: hs_bf dead after QKV projection

    // one-time opt-in for 128 KiB dynamic LDS (host-side state change; not a
    // stream op, safe under graph capture)
    static bool attr_done = false;
    if (!attr_done) {
        hipFuncSetAttribute(reinterpret_cast<const void*>(qkv_gemm),
                            hipFuncAttributeMaxDynamicSharedMemorySize, 131072);
        attr_done = true;
    }

    cast_all<<<dim3(9216), 256, 0, stream>>>(hs, Wq, Wk, Wv, Wo, hs_bf, Wq_bf,
                                             Wk_bf, Wv_bf, Wo_bf);

    qkv_gemm<<<dim3(192), 512, 131072, stream>>>(hs_bf, Wq_bf, Wk_bf, Wv_bf,
                                                 Qb, Kb, Vt, cosp, sinp);

    flash_attn_mfma<<<dim3(8, NH, BATCH), 256, 0, stream>>>(Qb, Kb, Vt, AO);

    gemm_bt<<<dim3(512), 256, 0, stream>>>(AO, Wo_bf, out, 4096, 2048, 2048);
}

// Round 8
// 279.056 us; speedup vs baseline: 1.0343x; 1.0336x over previous
//
#include <hip/hip_runtime.h>
#include <hip/hip_bf16.h>

#define BATCH 2
#define SEQ 2048
#define HID 2048
#define NH 32
#define NKVH 8
#define HD 64
#define GQ 4
#define ROT 32

typedef __attribute__((ext_vector_type(8))) short bf16x8;
typedef __attribute__((ext_vector_type(8))) unsigned short u16x8;
typedef __attribute__((ext_vector_type(4))) float f32x4;
typedef unsigned int u32;
typedef unsigned short u16;

#define MFMA_BF16(A, B, C) __builtin_amdgcn_mfma_f32_16x16x32_bf16(A, B, C, 0, 0, 0)

// 0.125 (1/sqrt(64)) * log2(e): folded into Q at projection time
#define QSCALE 0.180336880111120f

__device__ __forceinline__ void gload_lds16(const void* g, void* l) {
    __builtin_amdgcn_global_load_lds(
        (const __attribute__((address_space(1))) unsigned int*)g,
        (__attribute__((address_space(3))) unsigned int*)l, 16, 0, 0);
}

__device__ __forceinline__ u16 f2b(float x) {
    union { __hip_bfloat16 h; u16 u; } cv;
    cv.h = __float2bfloat16(x);
    return cv.u;
}
// round-half-up bf16 (values finite, non-NaN)
__device__ __forceinline__ u16 f2br(float x) {
    return (u16)((__builtin_bit_cast(u32, x) + 0x8000u) >> 16);
}
// round-half-up bf16x2 pack: (hi|lo) in 3 VALU ops (values finite, non-NaN)
__device__ __forceinline__ u32 pack2r(float lo, float hi) {
    u32 a = __builtin_bit_cast(u32, lo) + 0x8000u;
    u32 b = __builtin_bit_cast(u32, hi) + 0x8000u;
    return __builtin_amdgcn_perm(b, a, 0x07060302u);
}

// ---------------------------------------------------------------------------
// One fused cast dispatch: hs, Wq, Wk, Wv, Wo -> bf16. 2048 elems per block.
// ---------------------------------------------------------------------------
__global__ __launch_bounds__(256) void cast_all(
    const float* __restrict__ hs, const float* __restrict__ Wq,
    const float* __restrict__ Wk, const float* __restrict__ Wv,
    const float* __restrict__ Wo, u16* __restrict__ d_hs, u16* __restrict__ d_Wq,
    u16* __restrict__ d_Wk, u16* __restrict__ d_Wv, u16* __restrict__ d_Wo) {
    const int bx = blockIdx.x;
    const float* s;
    u16* d;
    int off;
    if (bx < 4096) { s = hs; d = d_hs; off = bx; }
    else if (bx < 6144) { s = Wq; d = d_Wq; off = bx - 4096; }
    else if (bx < 6656) { s = Wk; d = d_Wk; off = bx - 6144; }
    else if (bx < 7168) { s = Wv; d = d_Wv; off = bx - 6656; }
    else { s = Wo; d = d_Wo; off = bx - 7168; }
    const size_t i = (size_t)off * 2048 + threadIdx.x * 8;
    const float4 a = *(const float4*)&s[i];
    const float4 b = *(const float4*)&s[i + 4];
    u16x8 v;
    v[0] = f2b(a.x); v[1] = f2b(a.y); v[2] = f2b(a.z); v[3] = f2b(a.w);
    v[4] = f2b(b.x); v[5] = f2b(b.y); v[6] = f2b(b.z); v[7] = f2b(b.w);
    *(u16x8*)&d[i] = v;
}

// ---------------------------------------------------------------------------
// Fused QKV projection — 256x256 tile, 8 waves (2Mx4N), BK=64. EXACT r5 loop
// (best measured: 75.0 µs): 4-phase window, ph3 carries the window vmcnt(8)
// (tail vmcnt(0)), 8 barriers/window. r6's 2-phase merge regressed (80 µs) —
// barrier count is not the limiter; keep r5.
// SINGLE MFMA path for all modes (swapped operands, C^T in regs) — a
// per-mode if/else inside the MFMA chain blocks AGPR allocation of the
// 128-reg accumulator and spills it to scratch (round-1/2 failure).
// V's Vt[d][s] layout is recovered post-loop via a 128 KiB LDS transpose.
// ---------------------------------------------------------------------------
__global__ __launch_bounds__(512, 2) void qkv_gemm(
    const u16* __restrict__ A, const u16* __restrict__ Wq,
    const u16* __restrict__ Wk, const u16* __restrict__ Wv,
    u16* __restrict__ Qb, u16* __restrict__ Kb, u16* __restrict__ Vt,
    const float* __restrict__ cosp, const float* __restrict__ sinp) {
    extern __shared__ __align__(16) u16 lds[];
    u16* Asl = lds;             // [2 buf][2 half][128*64]
    u16* Wsl = lds + 32768;     // [2 buf][2 half][128*64]

    const int bid = blockIdx.x;                  // 192 blocks
    const int wg = (bid & 7) * 24 + (bid >> 3);  // bijective XCD chunk swizzle
    const int mt = wg / 12, nt = wg % 12;
    const int m0 = mt * 256;

    int mode, n0;
    const u16* __restrict__ W;
    if (nt < 8)       { mode = 0; W = Wq; n0 = nt * 256; }
    else if (nt < 10) { mode = 1; W = Wk; n0 = (nt - 8) * 256; }
    else              { mode = 2; W = Wv; n0 = (nt - 10) * 256; }

    const int tid = threadIdx.x;
    const int lane = tid & 63, w = tid >> 6;
    const int wr = w >> 2, wc = w & 3;           // 2 x 4 wave grid
    const int ar = lane & 15, quad = lane >> 4, q4 = quad * 4;

    f32x4 acc[8][4] = {};
    bf16x8 af[4][2], wf0[2][2], wf1[2][2];

// stage one quarter (64 rows = 8 KB = 1 gload/thread) of half h, tile tt,
// into ring buffer b. Global source pre-swizzled (chunk ^= row&7); LDS linear.
#define STAGE_A_Q(b, h, c, tt) { \
    const int ci_ = (c) * 512 + tid; \
    const int row_ = ci_ >> 3, kcg_ = (ci_ & 7) ^ (row_ & 7); \
    gload_lds16(&A[(size_t)(m0 + (h) * 128 + row_) * HID + (tt) * 64 + kcg_ * 8], \
                &Asl[((b) * 2 + (h)) * 8192 + ci_ * 8]); }
#define STAGE_W_Q(b, h, c, tt) { \
    const int ci_ = (c) * 512 + tid; \
    const int row_ = ci_ >> 3, kcg_ = (ci_ & 7) ^ (row_ & 7); \
    gload_lds16(&W[(size_t)(n0 + (h) * 128 + row_) * HID + (tt) * 64 + kcg_ * 8], \
                &Wsl[((b) * 2 + (h)) * 8192 + ci_ * 8]); }
// frag reads: wave wr owns A-half wr; wave's W-half = wc>>1, rows (wc&1)*64+
#define LDA_F(dst, mj, kh) { \
    const int r_ = (mj) * 16 + ar; \
    dst = *(const bf16x8*)&Asl[(cur * 2 + wr) * 8192 + r_ * 64 + \
                               ((((kh) * 4 + quad) ^ (r_ & 7)) * 8)]; }
#define LDW_F(dst, nj, kh) { \
    const int r_ = (wc & 1) * 64 + (nj) * 16 + ar; \
    dst = *(const bf16x8*)&Wsl[(cur * 2 + (wc >> 1)) * 8192 + r_ * 64 + \
                               ((((kh) * 4 + quad) ^ (r_ & 7)) * 8)]; }
// one C-quadrant (4 mi x 2 ni) x K=64: 16 MFMA. SINGLE PATH: swapped (C^T).
#define MFMA_QUAD(mh, nh, WF) \
    _Pragma("unroll") for (int kh = 0; kh < 2; ++kh) \
    _Pragma("unroll") for (int mi = 0; mi < 4; ++mi) \
    _Pragma("unroll") for (int ni = 0; ni < 2; ++ni) \
        acc[(mh) * 4 + mi][(nh) * 2 + ni] = \
            MFMA_BF16(WF[ni][kh], af[mi][kh], acc[(mh) * 4 + mi][(nh) * 2 + ni]);

    // prologue: tile 0 -> buf0 (first 8 loads), tile 1 -> buf1 (next 8).
    // vmcnt(8): tile 0 resident, tile 1 in flight.
    STAGE_A_Q(0, 0, 0, 0); STAGE_A_Q(0, 0, 1, 0);
    STAGE_A_Q(0, 1, 0, 0); STAGE_A_Q(0, 1, 1, 0);
    STAGE_W_Q(0, 0, 0, 0); STAGE_W_Q(0, 0, 1, 0);
    STAGE_W_Q(0, 1, 0, 0); STAGE_W_Q(0, 1, 1, 0);
    STAGE_A_Q(1, 0, 0, 1); STAGE_A_Q(1, 0, 1, 1);
    STAGE_A_Q(1, 1, 0, 1); STAGE_A_Q(1, 1, 1, 1);
    STAGE_W_Q(1, 0, 0, 1); STAGE_W_Q(1, 0, 1, 1);
    STAGE_W_Q(1, 1, 0, 1); STAGE_W_Q(1, 1, 1, 1);
    asm volatile("s_waitcnt vmcnt(8)" ::: "memory");
    __builtin_amdgcn_s_barrier();

#pragma unroll 2
    for (int t = 0; t < 32; ++t) {
        const int cur = t & 1;
        const bool st = (t < 30);    // windows 30/31 have nothing left to stage
        const int t2 = t + 2;
        // ---- ph0: read af rows 0-63 (half wr) + wf0; MFMA quad(0,0) ----
#pragma unroll
        for (int mi = 0; mi < 4; ++mi) { LDA_F(af[mi][0], mi, 0); LDA_F(af[mi][1], mi, 1); }
#pragma unroll
        for (int ni = 0; ni < 2; ++ni) { LDW_F(wf0[ni][0], ni, 0); LDW_F(wf0[ni][1], ni, 1); }
        __builtin_amdgcn_s_barrier();
        asm volatile("s_waitcnt lgkmcnt(0)" ::: "memory");
        __builtin_amdgcn_s_setprio(1);
        MFMA_QUAD(0, 0, wf0);
        __builtin_amdgcn_s_setprio(0);
        __builtin_amdgcn_s_barrier();
        // ---- ph1: read wf1; stage A(t+2) c0 (both halves); MFMA quad(0,1) ----
#pragma unroll
        for (int ni = 0; ni < 2; ++ni) { LDW_F(wf1[ni][0], 2 + ni, 0); LDW_F(wf1[ni][1], 2 + ni, 1); }
        if (st) { STAGE_A_Q(cur, 0, 0, t2); STAGE_A_Q(cur, 1, 0, t2); }
        __builtin_amdgcn_s_barrier();
        asm volatile("s_waitcnt lgkmcnt(0)" ::: "memory");
        __builtin_amdgcn_s_setprio(1);
        MFMA_QUAD(0, 1, wf1);
        __builtin_amdgcn_s_setprio(0);
        __builtin_amdgcn_s_barrier();
        // ---- ph2: read af rows 64-127; stage W(t+2) h0; MFMA quad(1,1) ----
#pragma unroll
        for (int mi = 0; mi < 4; ++mi) { LDA_F(af[mi][0], 4 + mi, 0); LDA_F(af[mi][1], 4 + mi, 1); }
        if (st) { STAGE_W_Q(cur, 0, 0, t2); STAGE_W_Q(cur, 0, 1, t2); }
        __builtin_amdgcn_s_barrier();
        asm volatile("s_waitcnt lgkmcnt(0)" ::: "memory");
        __builtin_amdgcn_s_setprio(1);
        MFMA_QUAD(1, 1, wf1);
        __builtin_amdgcn_s_setprio(0);
        __builtin_amdgcn_s_barrier();
        // ---- ph3: stage A(t+2) c1 + W(t+2) h1; window vmcnt; MFMA quad(1,0).
        //      Post-MFMA barrier doubles as next window's entry guard. ----
        if (st) {
            STAGE_A_Q(cur, 0, 1, t2); STAGE_A_Q(cur, 1, 1, t2);
            STAGE_W_Q(cur, 1, 0, t2); STAGE_W_Q(cur, 1, 1, t2);
            // tile t+1's 8 loads (oldest) retired; tile t+2's 8 stay in flight
            asm volatile("s_waitcnt vmcnt(8)" ::: "memory");
        } else {
            asm volatile("s_waitcnt vmcnt(0)" ::: "memory");
        }
        __builtin_amdgcn_s_barrier();
        __builtin_amdgcn_s_setprio(1);
        MFMA_QUAD(1, 0, wf0);
        __builtin_amdgcn_s_setprio(0);
        __builtin_amdgcn_s_barrier();
    }

#undef STAGE_A_Q
#undef STAGE_W_Q
#undef LDA_F
#undef LDW_F
#undef MFMA_QUAD

    // C^T regs (all modes): acc[mi][ni][r] =
    //   C[token = m0+wr*128+mi*16+ar][col = n0+wc*64+ni*16+q4+r]
    if (mode < 2) {
        const float SC = (mode == 0) ? QSCALE : 1.0f;
        u16* __restrict__ C = (mode == 0) ? Qb : Kb;
        const int N = (mode == 0) ? 2048 : 512;
#pragma unroll
        for (int mi = 0; mi < 8; ++mi) {
            const int t = m0 + wr * 128 + mi * 16 + ar;
            const float4 c0 = *(const float4*)&cosp[(size_t)t * ROT + q4];
            const float4 s0 = *(const float4*)&sinp[(size_t)t * ROT + q4];
            const float4 c1 = *(const float4*)&cosp[(size_t)t * ROT + 16 + q4];
            const float4 s1 = *(const float4*)&sinp[(size_t)t * ROT + 16 + q4];
            u16* crow = &C[(size_t)t * N + n0 + wc * 64];
            const f32x4 x0 = acc[mi][0], x1 = acc[mi][1];
            const float cr0[4] = {c0.x, c0.y, c0.z, c0.w};
            const float sr0[4] = {s0.x, s0.y, s0.z, s0.w};
            const float cr1[4] = {c1.x, c1.y, c1.z, c1.w};
            const float sr1[4] = {s1.x, s1.y, s1.z, s1.w};
            float o0[4], o1[4];
#pragma unroll
            for (int r = 0; r < 4; ++r) {
                o0[r] = (x0[r] * cr0[r] - x1[r] * sr0[r]) * SC;
                o1[r] = (x1[r] * cr1[r] + x0[r] * sr1[r]) * SC;
            }
            uint2 v;
            v.x = pack2r(o0[0], o0[1]); v.y = pack2r(o0[2], o0[3]);
            *(uint2*)&crow[q4] = v;
            v.x = pack2r(o1[0], o1[1]); v.y = pack2r(o1[2], o1[3]);
            *(uint2*)&crow[16 + q4] = v;
            v.x = pack2r(acc[mi][2][0] * SC, acc[mi][2][1] * SC);
            v.y = pack2r(acc[mi][2][2] * SC, acc[mi][2][3] * SC);
            *(uint2*)&crow[32 + q4] = v;
            v.x = pack2r(acc[mi][3][0] * SC, acc[mi][3][1] * SC);
            v.y = pack2r(acc[mi][3][2] * SC, acc[mi][3][3] * SC);
            *(uint2*)&crow[48 + q4] = v;
        }
    } else {
        // V epilogue: transpose C^T -> Vt[d][s] through LDS (staging LDS dead).
        // Lt[vcol][tok ^ xsw(vcol)], xsw = ((vcol>>2)&3)<<4 (bank-spreads quads).
        u16* Lt = lds;  // 256 x 256 bf16 = 128 KiB
        __syncthreads();   // all waves' outstanding gloads drained (ph3 vmcnt(0))
#pragma unroll
        for (int mi = 0; mi < 8; ++mi) {
            const int tok = wr * 128 + mi * 16 + ar;
#pragma unroll
            for (int ni = 0; ni < 4; ++ni) {
                const int vc = wc * 64 + ni * 16 + q4;
#pragma unroll
                for (int r = 0; r < 4; ++r) {
                    const int vcol = vc + r;
                    const int ti = tok ^ (((vcol >> 2) & 3) << 4);
                    Lt[vcol * 256 + ti] = f2br(acc[mi][ni][r]);
                }
            }
        }
        __syncthreads();
        // read back token-contiguous; store coalesced with pi relabeling
        for (int it = 0; it < 32; ++it) {
            const int vcol = it * 8 + w;
            const int gcol = n0 + vcol;
            const int kvh = gcol >> 6, d = gcol & 63;
            const int xsw = ((vcol >> 2) & 3) << 4;
            const int s0l = lane * 4;
            const uint2 vv = *(const uint2*)&Lt[vcol * 256 + (s0l ^ xsw)];
            const int g = m0 + s0l;
            const int bb = g >> 11;
            const int s = g & 2047;
            const int ca = (s >> 2) & 7;
            const int cl = ((ca & 3) << 1) | (ca >> 2);
            const int spos = (s & ~31) + cl * 4;
            *(uint2*)&Vt[((size_t)(bb * NKVH + kvh) * HD + d) * SEQ + spos] = vv;
        }
    }
}

// ---------------------------------------------------------------------------
// O projection: C[M=4096, N=2048] = A[M,K] @ W[N,K]^T, fp32 out.
// r7: 256x128 tile, 256 blocks = EXACTLY 1/CU (100% fill; old 128² version
// ran 512 blocks in 2 rounds at the round-0 per-CU rate, ~57 µs est).
// r5 qkv 4-phase counted-vmcnt schedule ported: 8 waves (2Mx4N), per-wave
// 128x32 out (acc[8][2]); LDS 96 KiB ring (A 2buf x 2half x 16KB, W 2buf x
// 16KB); 6 loads/K-tile -> vmcnt(6) window guard in ph3; 4 phases x 8 MFMA.
// Single MFMA path, swapped operands (C^T in regs), float4 stores.
// ---------------------------------------------------------------------------
__global__ __launch_bounds__(512, 2) void gemm_bt(const u16* __restrict__ A,
                                                  const u16* __restrict__ W,
                                                  float* __restrict__ C,
                                                  int M, int N, int K) {
    extern __shared__ __align__(16) u16 lds[];
    u16* Asl = lds;              // [2 buf][2 half][128*64] = 64 KiB
    u16* Wsl = lds + 32768;      // [2 buf][128*64] = 32 KiB

    const int bid = blockIdx.x;                   // 256 blocks
    const int wg = (bid & 7) * 32 + (bid >> 3);   // XCD chunk swizzle (256%8==0)
    const int mt = wg >> 4, nt = wg & 15;
    const int m0 = mt * 256, n0 = nt * 128;

    const int tid = threadIdx.x;
    const int lane = tid & 63, w = tid >> 6;
    const int wr = w >> 2, wc = w & 3;            // 2 x 4 wave grid
    const int ar = lane & 15, quad = lane >> 4, q4 = quad * 4;

    f32x4 acc[8][2] = {};
    bf16x8 af[4][2], wf0[2], wf1[2];

#define GB_STAGE_A(b, h, c, tt) { \
    const int ci_ = (c) * 512 + tid; \
    const int row_ = ci_ >> 3, kcg_ = (ci_ & 7) ^ (row_ & 7); \
    gload_lds16(&A[(size_t)(m0 + (h) * 128 + row_) * K + (tt) * 64 + kcg_ * 8], \
                &Asl[((b) * 2 + (h)) * 8192 + ci_ * 8]); }
#define GB_STAGE_W(b, c, tt) { \
    const int ci_ = (c) * 512 + tid; \
    const int row_ = ci_ >> 3, kcg_ = (ci_ & 7) ^ (row_ & 7); \
    gload_lds16(&W[(size_t)(n0 + row_) * K + (tt) * 64 + kcg_ * 8], \
                &Wsl[(b) * 8192 + ci_ * 8]); }
#define GB_LDA(dst, mj, kh) { \
    const int r_ = (mj) * 16 + ar; \
    dst = *(const bf16x8*)&Asl[(cur * 2 + wr) * 8192 + r_ * 64 + \
                               ((((kh) * 4 + quad) ^ (r_ & 7)) * 8)]; }
#define GB_LDW(dst, nj, kh) { \
    const int r_ = wc * 32 + (nj) * 16 + ar; \
    dst = *(const bf16x8*)&Wsl[cur * 8192 + r_ * 64 + \
                               ((((kh) * 4 + quad) ^ (r_ & 7)) * 8)]; }
#define GB_MFMA(mh, nj, WF) \
    _Pragma("unroll") for (int kh = 0; kh < 2; ++kh) \
    _Pragma("unroll") for (int mi = 0; mi < 4; ++mi) \
        acc[(mh) * 4 + mi][nj] = MFMA_BF16(WF[kh], af[mi][kh], acc[(mh) * 4 + mi][nj]);

    // prologue: tiles 0,1; per tile order Ac0(h0,h1), W(c0,c1), Ac1(h0,h1)
    GB_STAGE_A(0, 0, 0, 0); GB_STAGE_A(0, 1, 0, 0);
    GB_STAGE_W(0, 0, 0);    GB_STAGE_W(0, 1, 0);
    GB_STAGE_A(0, 0, 1, 0); GB_STAGE_A(0, 1, 1, 0);
    GB_STAGE_A(1, 0, 0, 1); GB_STAGE_A(1, 1, 0, 1);
    GB_STAGE_W(1, 0, 1);    GB_STAGE_W(1, 1, 1);
    GB_STAGE_A(1, 0, 1, 1); GB_STAGE_A(1, 1, 1, 1);
    asm volatile("s_waitcnt vmcnt(6)" ::: "memory");
    __builtin_amdgcn_s_barrier();

#pragma unroll 2
    for (int t = 0; t < 32; ++t) {
        const int cur = t & 1;
        const bool st = (t < 30);
        const int t2 = t + 2;
        // ---- ph0: read af rows 0-63 + wf0; MFMA (mh0, nj0) ----
#pragma unroll
        for (int mi = 0; mi < 4; ++mi) { GB_LDA(af[mi][0], mi, 0); GB_LDA(af[mi][1], mi, 1); }
        GB_LDW(wf0[0], 0, 0); GB_LDW(wf0[1], 0, 1);
        __builtin_amdgcn_s_barrier();
        asm volatile("s_waitcnt lgkmcnt(0)" ::: "memory");
        __builtin_amdgcn_s_setprio(1);
        GB_MFMA(0, 0, wf0);
        __builtin_amdgcn_s_setprio(0);
        __builtin_amdgcn_s_barrier();
        // ---- ph1: read wf1; stage A(t+2) c0; MFMA (mh0, nj1) ----
        GB_LDW(wf1[0], 1, 0); GB_LDW(wf1[1], 1, 1);
        if (st) { GB_STAGE_A(cur, 0, 0, t2); GB_STAGE_A(cur, 1, 0, t2); }
        __builtin_amdgcn_s_barrier();
        asm volatile("s_waitcnt lgkmcnt(0)" ::: "memory");
        __builtin_amdgcn_s_setprio(1);
        GB_MFMA(0, 1, wf1);
        __builtin_amdgcn_s_setprio(0);
        __builtin_amdgcn_s_barrier();
        // ---- ph2: read af rows 64-127; stage W(t+2); MFMA (mh1, nj1) ----
#pragma unroll
        for (int mi = 0; mi < 4; ++mi) { GB_LDA(af[mi][0], 4 + mi, 0); GB_LDA(af[mi][1], 4 + mi, 1); }
        if (st) { GB_STAGE_W(cur, 0, t2); GB_STAGE_W(cur, 1, t2); }
        __builtin_amdgcn_s_barrier();
        asm volatile("s_waitcnt lgkmcnt(0)" ::: "memory");
        __builtin_amdgcn_s_setprio(1);
        GB_MFMA(1, 1, wf1);
        __builtin_amdgcn_s_setprio(0);
        __builtin_amdgcn_s_barrier();
        // ---- ph3: stage A(t+2) c1; window vmcnt; MFMA (mh1, nj0) ----
        if (st) {
            GB_STAGE_A(cur, 0, 1, t2); GB_STAGE_A(cur, 1, 1, t2);
            // tile t+1's 6 loads (oldest) retired; tile t+2's 6 in flight
            asm volatile("s_waitcnt vmcnt(6)" ::: "memory");
        } else {
            asm volatile("s_waitcnt vmcnt(0)" ::: "memory");
        }
        __builtin_amdgcn_s_barrier();
        __builtin_amdgcn_s_setprio(1);
        GB_MFMA(1, 0, wf0);
        __builtin_amdgcn_s_setprio(0);
        __builtin_amdgcn_s_barrier();
    }

#undef GB_STAGE_A
#undef GB_STAGE_W
#undef GB_LDA
#undef GB_LDW
#undef GB_MFMA

    // C^T regs: acc[mi][ni][r] = C[m0+wr*128+mi*16+ar][n0+wc*32+ni*16+q4+r]
#pragma unroll
    for (int mi = 0; mi < 8; ++mi) {
        const int t = m0 + wr * 128 + mi * 16 + ar;
#pragma unroll
        for (int ni = 0; ni < 2; ++ni) {
            float4 v = {acc[mi][ni][0], acc[mi][ni][1], acc[mi][ni][2], acc[mi][ni][3]};
            *(float4*)&C[(size_t)t * N + n0 + wc * 32 + ni * 16 + q4] = v;
        }
    }
}

// ---------------------------------------------------------------------------
// Flash attention, S^T formulation, causal-balanced: block p handles q-tiles
// p and 15-p (uniform 34 kv-iters). 128 q rows per phase, 32/wave.
// S^T = K*Q^T (lane owns q); O^T = V^T*P^T (own post-exp regs ARE the P^T
// B-frag under the kv relabeling baked into Vt). Max-free streaming softmax.
// VALU cuts (r4): raw v_exp_f32, zero-C first MFMA, hoisted rofs/gptrs.
// No setprio: 4-wave lockstep block is m190's negative regime (r5: −9 µs).
// ---------------------------------------------------------------------------
__global__ __launch_bounds__(256, 2) void flash_attn_mfma(
    const u16* __restrict__ Qg, const u16* __restrict__ Kg,
    const u16* __restrict__ Vtg, u16* __restrict__ AO) {
    const int p = blockIdx.x, h = blockIdx.y, b = blockIdx.z;
    const int kvh = h / GQ;
    const int tid = threadIdx.x;
    const int lane = tid & 63, w = tid >> 6;
    const int n = lane & 15, quad = lane >> 4;

    __shared__ __align__(16) u16 Qs[128 * 64];
    __shared__ __align__(16) u16 Ks[2 * 64 * 64];
    __shared__ __align__(16) u16 Vts[2 * 64 * 64];

    // hoisted LDS fragment offsets: rofs[j][t16] for row=t16*16+n, chunk j
    // (same formula serves K reads [kh][krow] and V reads [kb][drow])
    int rofs[2][4];
#pragma unroll
    for (int j = 0; j < 2; ++j)
#pragma unroll
        for (int t16 = 0; t16 < 4; ++t16) {
            const int row = t16 * 16 + n;
            rofs[j][t16] = row * 64 + (((j * 4 + quad) ^ (row & 7)) * 8);
        }

    // hoisted global staging pointers (per-thread, kv-tile 0)
    const int ci0 = tid, ci1 = 256 + tid;
    const int row0 = ci0 >> 3, kcg0 = (ci0 & 7) ^ (row0 & 7);
    const int row1 = ci1 >> 3, kcg1 = (ci1 & 7) ^ (row1 & 7);
    const u16* kg0 = &Kg[(size_t)((b * SEQ + row0) * NKVH + kvh) * HD + kcg0 * 8];
    const u16* kg1 = &Kg[(size_t)((b * SEQ + row1) * NKVH + kvh) * HD + kcg1 * 8];
    const u16* vg0 = &Vtg[(size_t)((b * NKVH + kvh) * HD + row0) * SEQ + kcg0 * 8];
    const u16* vg1 = &Vtg[(size_t)((b * NKVH + kvh) * HD + row1) * SEQ + kcg1 * 8];
    const f32x4 kZ = {0.f, 0.f, 0.f, 0.f};

    for (int ph = 0; ph < 2; ++ph) {
        const int bq = ph ? (15 - p) : p;
        const int q0 = bq * 128;

        // stage Q (128x64) and K/V tile 0 into buffer 0 (chunk ^= row&7)
#pragma unroll
        for (int it = 0; it < 4; ++it) {
            const int ci = it * 256 + tid;
            const int row = ci >> 3, kcg = (ci & 7) ^ (row & 7);
            gload_lds16(&Qg[(size_t)((b * SEQ + q0 + row) * NH + h) * HD + kcg * 8],
                        &Qs[ci * 8]);
        }
        gload_lds16(kg0, &Ks[ci0 * 8]);
        gload_lds16(kg1, &Ks[ci1 * 8]);
        gload_lds16(vg0, &Vts[ci0 * 8]);
        gload_lds16(vg1, &Vts[ci1 * 8]);
        __syncthreads();

        // hoist Q^T B-frags
        bf16x8 Qf[2][2];
#pragma unroll
        for (int t = 0; t < 2; ++t)
#pragma unroll
            for (int kh = 0; kh < 2; ++kh) {
                const int qrow = w * 32 + t * 16 + n;
                const int c = (kh * 4 + quad) ^ (qrow & 7);
                Qf[t][kh] = *(const bf16x8*)&Qs[qrow * 64 + c * 8];
            }

        f32x4 O[2][4] = {};
        float lsum[2] = {0.f, 0.f};

        const int ktmax = 2 * bq + 1;
        for (int kt = 0; kt <= ktmax; ++kt) {
            const int cur = kt & 1;
            if (kt < ktmax) {  // prefetch next K/V tile into other buffer
                const int base = (cur ^ 1) * 4096;
                const size_t ko = (size_t)(kt + 1) * (64 * NKVH * HD);
                const size_t vo = (size_t)(kt + 1) * 64;
                gload_lds16(kg0 + ko, &Ks[base + ci0 * 8]);
                gload_lds16(kg1 + ko, &Ks[base + ci1 * 8]);
                gload_lds16(vg0 + vo, &Vts[base + ci0 * 8]);
                gload_lds16(vg1 + vo, &Vts[base + ci1 * 8]);
            }
            const u16* Kl = &Ks[cur * 4096];
            const u16* Vl = &Vts[cur * 4096];

            // S^T (log2-scaled domain; Q pre-scaled); zero-C first MFMA
            f32x4 sc[2][4];
#pragma unroll
            for (int k4 = 0; k4 < 4; ++k4) {
                const bf16x8 Kf0 = *(const bf16x8*)&Kl[rofs[0][k4]];
                sc[0][k4] = MFMA_BF16(Kf0, Qf[0][0], kZ);
                sc[1][k4] = MFMA_BF16(Kf0, Qf[1][0], kZ);
                const bf16x8 Kf1 = *(const bf16x8*)&Kl[rofs[1][k4]];
                sc[0][k4] = MFMA_BF16(Kf1, Qf[0][1], sc[0][k4]);
                sc[1][k4] = MFMA_BF16(Kf1, Qf[1][1], sc[1][k4]);
            }

            const bool masked = (kt >= 2 * bq);
            bf16x8 Pf[2][2];
#pragma unroll
            for (int t = 0; t < 2; ++t) {
                const int qg = q0 + w * 32 + t * 16 + n;
                if (masked) {
#pragma unroll
                    for (int k4 = 0; k4 < 4; ++k4)
#pragma unroll
                        for (int r = 0; r < 4; ++r)
                            if (kt * 64 + k4 * 16 + quad * 4 + r > qg)
                                sc[t][k4][r] = -1e30f;  // exp2 -> 0
                }
                float sk[4];
#pragma unroll
                for (int k4 = 0; k4 < 4; ++k4) {
                    const float e0 = __builtin_amdgcn_exp2f(sc[t][k4][0]);
                    const float e1 = __builtin_amdgcn_exp2f(sc[t][k4][1]);
                    const float e2 = __builtin_amdgcn_exp2f(sc[t][k4][2]);
                    const float e3 = __builtin_amdgcn_exp2f(sc[t][k4][3]);
                    sc[t][k4][0] = e0; sc[t][k4][1] = e1;
                    sc[t][k4][2] = e2; sc[t][k4][3] = e3;
                    sk[k4] = (e0 + e1) + (e2 + e3);
                }
                lsum[t] += (sk[0] + sk[1]) + (sk[2] + sk[3]);
#pragma unroll
                for (int kb = 0; kb < 2; ++kb) {
                    union { u32 uw[4]; bf16x8 v; } cv;
#pragma unroll
                    for (int a = 0; a < 2; ++a) {
                        cv.uw[a * 2 + 0] = pack2r(sc[t][2 * kb + a][0], sc[t][2 * kb + a][1]);
                        cv.uw[a * 2 + 1] = pack2r(sc[t][2 * kb + a][2], sc[t][2 * kb + a][3]);
                    }
                    Pf[t][kb] = cv.v;
                }
            }

            // O^T += V^T * P^T
#pragma unroll
            for (int kb = 0; kb < 2; ++kb)
#pragma unroll
                for (int dt = 0; dt < 4; ++dt) {
                    const bf16x8 Vf = *(const bf16x8*)&Vl[rofs[kb][dt]];
                    O[0][dt] = MFMA_BF16(Vf, Pf[0][kb], O[0][dt]);
                    O[1][dt] = MFMA_BF16(Vf, Pf[1][kb], O[1][dt]);
                }
            __syncthreads();
        }

        // epilogue: reduce l across quads once; O^T regs: d=dt*16+quad*4+r, q=n
#pragma unroll
        for (int t = 0; t < 2; ++t) {
            float rs = lsum[t];
            rs += __shfl_xor(rs, 16, 64);
            rs += __shfl_xor(rs, 32, 64);
            const int qg = q0 + w * 32 + t * 16 + n;
            const float inv = 1.f / rs;
#pragma unroll
            for (int dt = 0; dt < 4; ++dt) {
                uint2 v2;
                v2.x = pack2r(O[t][dt][0] * inv, O[t][dt][1] * inv);
                v2.y = pack2r(O[t][dt][2] * inv, O[t][dt][3] * inv);
                *(uint2*)&AO[(size_t)((b * SEQ + qg) * NH + h) * HD + dt * 16 + quad * 4] = v2;
            }
        }
    }
}

// ---------------------------------------------------------------------------
extern "C" void kernel_launch(void* const* d_in, const int* in_sizes, int n_in,
                              void* d_out, int out_size, void* d_ws,
                              size_t ws_size, hipStream_t stream) {
    const float* hs = (const float*)d_in[0];
    const float* cosp = (const float*)d_in[1];
    const float* sinp = (const float*)d_in[2];
    // d_in[3] attention_mask: pure causal, handled in-kernel
    const float* Wq = (const float*)d_in[4];
    const float* Wk = (const float*)d_in[5];
    const float* Wv = (const float*)d_in[6];
    const float* Wo = (const float*)d_in[7];
    float* out = (float*)d_out;

    u16* ws = (u16*)d_ws;
    u16* hs_bf = ws;
    u16* Wq_bf = hs_bf + (size_t)4096 * 2048;
    u16* Wk_bf = Wq_bf + (size_t)2048 * 2048;
    u16* Wv_bf = Wk_bf + (size_t)512 * 2048;
    u16* Wo_bf = Wv_bf + (size_t)512 * 2048;
    u16* Qb = Wo_bf + (size_t)2048 * 2048;
    u16* Kb = Qb + (size_t)4096 * 2048;
    u16* Vt = Kb + (size_t)4096 * 512;
    u16* AO = hs_bf;  // alias: hs_bf dead after QKV projection

    // one-time opt-in for large dynamic LDS (host-side state change; not a
    // stream op, safe under graph capture)
    static bool attr_done = false;
    if (!attr_done) {
        hipFuncSetAttribute(reinterpret_cast<const void*>(qkv_gemm),
                            hipFuncAttributeMaxDynamicSharedMemorySize, 131072);
        hipFuncSetAttribute(reinterpret_cast<const void*>(gemm_bt),
                            hipFuncAttributeMaxDynamicSharedMemorySize, 98304);
        attr_done = true;
    }

    cast_all<<<dim3(9216), 256, 0, stream>>>(hs, Wq, Wk, Wv, Wo, hs_bf, Wq_bf,
                                             Wk_bf, Wv_bf, Wo_bf);

    qkv_gemm<<<dim3(192), 512, 131072, stream>>>(hs_bf, Wq_bf, Wk_bf, Wv_bf,
                                                 Qb, Kb, Vt, cosp, sinp);

    flash_attn_mfma<<<dim3(8, NH, BATCH), 256, 0, stream>>>(Qb, Kb, Vt, AO);

    gemm_bt<<<dim3(256), 512, 98304, stream>>>(AO, Wo_bf, out, 4096, 2048, 2048);
}